// Round 10
// baseline (84.392 us; speedup 1.0000x reference)
//
#include <hip/hip_runtime.h>
#include <stdint.h>

// Square-attack schedule collapse for B=1, C=3, H=224, EPS=0.05, N_QUERIES=5000.
//
// R8: PASS absmax 0.0 at 71.4 us; ~40 us of that is the harness's 0xAA poison
// fill of d_ws (268 MB @ 84% HBM peak, visible as fillBufferAligned) -- a fixed
// floor. Controllable part ~31 us across 3 kernels + 2 graph gaps.
// R9: fuse step-param RNG + table build into ONE single-block kernel (params
// never touch global; atomicMax bins fed directly from registers), deleting a
// dispatch, a dependency gap, and the sp round-trip.
//
// RNG: JAX threefry2x32, jax_threefry_partitionable=True (verified exact):
//   fold_in(key, d)          = tf(key, (0, d))
//   split(k)                 = k1 = tf(k,(0,0)), k2 = tf(k,(0,1))
//   random_bits(key,32,n)[i] = X0 ^ X1 of tf(key, (0, i))

#define HH 224
#define NQ 5000
#define NPIX (HH * HH)      // 50176 = 196 * 256
#define EPSF 0.05f
#define NTAB (8 * 3 * 8 * 224)   // [seg][c][k][v] u16 = 43008 elems = 86016 B

__device__ __forceinline__ void tf2x32(uint32_t k0, uint32_t k1,
                                       uint32_t x0, uint32_t x1,
                                       uint32_t& o0, uint32_t& o1) {
  uint32_t ks2 = k0 ^ k1 ^ 0x1BD11BDAu;
  x0 += k0; x1 += k1;
#define TFR(r) { x0 += x1; x1 = (x1 << (r)) | (x1 >> (32 - (r))); x1 ^= x0; }
  TFR(13) TFR(15) TFR(26) TFR(6)
  x0 += k1;  x1 += ks2 + 1u;
  TFR(17) TFR(29) TFR(16) TFR(24)
  x0 += ks2; x1 += k0 + 2u;
  TFR(13) TFR(15) TFR(26) TFR(6)
  x0 += k0;  x1 += k1 + 3u;
  TFR(17) TFR(29) TFR(16) TFR(24)
  x0 += k1;  x1 += ks2 + 4u;
  TFR(13) TFR(15) TFR(26) TFR(6)
  x0 += ks2; x1 += k0 + 5u;
#undef TFR
  o0 = x0; o1 = x1;
}

__device__ __forceinline__ int sign_from_bits(uint32_t bits) {
  uint32_t mant = bits >> 9;
  return (mant > 0x400000u) ? 1 : ((mant < 0x400000u) ? -1 : 0);
}

__device__ __forceinline__ float u01_from_bits(uint32_t bits) {
  return __uint_as_float(0x3f800000u | (bits >> 9)) - 1.0f;
}

// static schedule: s = round(224*sqrt(p(t))) per _p_selection; verified exact
__device__ __forceinline__ int s_of(int t) {
  if (t <= 10)   return 200;
  if (t <= 50)   return 142;
  if (t <= 200)  return 100;
  if (t <= 500)  return 71;
  if (t <= 1000) return 50;
  if (t <= 2000) return 35;
  if (t <= 4000) return 25;
  return 18;
}

__device__ __forceinline__ int seg_of(int t) {
  if (t <= 10)   return 0;
  if (t <= 50)   return 1;
  if (t <= 200)  return 2;
  if (t <= 500)  return 3;
  if (t <= 1000) return 4;
  if (t <= 2000) return 5;
  if (t <= 4000) return 6;
  return 7;
}

// --- Kernel 1 (single block, 1024 threads): per-step RNG -> atomicMax bins
// -> sparse range-max tree -> write 86 KB table + 672 init signs to global.
__global__ __launch_bounds__(1024) void fused_build_kernel(uint16_t* __restrict__ gtab,
                                                           int8_t* __restrict__ gisign) {
  __shared__ uint32_t bins[8 * 3 * 224];   // [seg][c][v]  21504 B
  __shared__ uint16_t tab[NTAB];           // 86016 B
  int tid = threadIdx.x;
  for (int i = tid; i < 8 * 3 * 224; i += 1024) bins[i] = 0;
  __syncthreads();

  // 5000 steps, 5 per thread; params stay in registers, feed bins directly.
  for (int t = tid; t < NQ; t += 1024) {
    uint32_t f0, f1;
    tf2x32(0u, 1u, 0u, (uint32_t)(t + 1), f0, f1);      // k = fold_in(base, t+1)
    uint32_t a0, a1, b0, b1;
    tf2x32(f0, f1, 0u, 0u, a0, a1);                     // k1 = tf(k, (0,0))
    tf2x32(f0, f1, 0u, 1u, b0, b1);                     // k2 = tf(k, (0,1))
    uint32_t u0, u1;
    tf2x32(a0, a1, 0u, 0u, u0, u1);                     // scalar uniform bits
    int s = s_of(t);
    int vh = (int)floorf(u01_from_bits(u0 ^ u1) * (float)(HH - s));
    uint32_t c0, c1;
    tf2x32(b0, b1, 0u, 0u, c0, c1);
    int g0 = sign_from_bits(c0 ^ c1);
    tf2x32(b0, b1, 0u, 1u, c0, c1);
    int g1 = sign_from_bits(c0 ^ c1);
    tf2x32(b0, b1, 0u, 2u, c0, c1);
    int g2 = sign_from_bits(c0 ^ c1);
    int base = seg_of(t) * 3 * 224;
    uint32_t val = ((uint32_t)(t + 1)) << 1;
    if (g0) atomicMax(&bins[base + vh],       val | (uint32_t)(g0 > 0));
    if (g1) atomicMax(&bins[base + 224 + vh], val | (uint32_t)(g1 > 0));
    if (g2) atomicMax(&bins[base + 448 + vh], val | (uint32_t)(g2 > 0));
  }

  // init stripe signs: k0 = fold_in(base, 0); bits[n] = X0^X1 of tf(k0,(0,n))
  if (tid < 3 * HH) {
    uint32_t g0, g1;
    tf2x32(0u, 1u, 0u, 0u, g0, g1);
    uint32_t o0, o1;
    tf2x32(g0, g1, 0u, (uint32_t)tid, o0, o1);
    gisign[tid] = (int8_t)sign_from_bits(o0 ^ o1);
  }
  __syncthreads();

  for (int i = tid; i < 8 * 3 * 224; i += 1024) {   // tree level 0
    int sc = i / 224, v = i % 224;
    tab[(sc * 8) * 224 + v] = (uint16_t)bins[i];
  }
  __syncthreads();
  for (int k = 1; k < 8; ++k) {
    int w = 1 << (k - 1);
    for (int i = tid; i < 8 * 3 * 224; i += 1024) {
      int sc = i / 224, v = i % 224;
      uint16_t a = tab[(sc * 8 + k - 1) * 224 + v];
      uint16_t b = (v + w < 224) ? tab[(sc * 8 + k - 1) * 224 + v + w] : (uint16_t)0;
      tab[(sc * 8 + k) * 224 + v] = (a > b) ? a : b;
    }
    __syncthreads();
  }
  const uint32_t* t32 = (const uint32_t*)tab;
  uint32_t* g32 = (uint32_t*)gtab;
  for (int i = tid; i < NTAB / 2; i += 1024) g32[i] = t32[i];
}

// --- Kernel 2: stage table to LDS; per pixel, 8 O(1) range-max queries per
// channel (48 independent u16 LDS loads); emit rail value.
__global__ __launch_bounds__(256) void resolve_kernel(const uint16_t* __restrict__ gtab,
                                                      const int8_t* __restrict__ isign,
                                                      const float* __restrict__ x,
                                                      float* __restrict__ out) {
  __shared__ uint16_t tab[NTAB];           // 86016 B
  {
    float4* t4 = (float4*)tab;
    const float4* g4 = (const float4*)gtab;
    for (int i = threadIdx.x; i < NTAB * 2 / 16; i += 256) t4[i] = g4[i];
  }
  __syncthreads();

  int p = blockIdx.x * 256 + threadIdx.x;   // 0..50175
  int pi = p / HH, pj = p % HH;
  int m = min(pi, pj), M = max(pi, pj);

  const int SEG_S[8] = {200, 142, 100, 71, 50, 35, 25, 18};
  uint32_t best0 = 0, best1 = 0, best2 = 0;
#pragma unroll
  for (int seg = 0; seg < 8; ++seg) {
    const int s = SEG_S[seg];
    int lo = max(0, M - s + 1);
    int hi = min(m, 223 - s);
    bool ok = (lo <= hi);
    int len = ok ? (hi - lo + 1) : 1;
    int k = 31 - __clz(len);
    int o2 = hi + 1 - (1 << k);             // >= lo >= 0 when ok; == hi when !ok
    int b = seg * 5376 + k * 224;           // c stride = 8*224 = 1792
    uint32_t v0 = max((uint32_t)tab[b + lo],        (uint32_t)tab[b + o2]);
    uint32_t v1 = max((uint32_t)tab[b + 1792 + lo], (uint32_t)tab[b + 1792 + o2]);
    uint32_t v2 = max((uint32_t)tab[b + 3584 + lo], (uint32_t)tab[b + 3584 + o2]);
    if (!ok) { v0 = 0u; v1 = 0u; v2 = 0u; }
    best0 = max(best0, v0);
    best1 = max(best1, v1);
    best2 = max(best2, v2);
  }

  int s0 = best0 ? ((best0 & 1u) ? 1 : -1) : (int)isign[pj];
  int s1 = best1 ? ((best1 & 1u) ? 1 : -1) : (int)isign[HH + pj];
  int s2 = best2 ? ((best2 & 1u) ? 1 : -1) : (int)isign[2 * HH + pj];

  float x0 = x[p];
  float x1 = x[NPIX + p];
  float x2 = x[2 * NPIX + p];
  out[p]            = (s0 > 0) ? fminf(x0 + EPSF, 1.0f)
                    : (s0 < 0) ? fmaxf(x0 - EPSF, 0.0f)
                               : fminf(fmaxf(x0, 0.0f), 1.0f);
  out[NPIX + p]     = (s1 > 0) ? fminf(x1 + EPSF, 1.0f)
                    : (s1 < 0) ? fmaxf(x1 - EPSF, 0.0f)
                               : fminf(fmaxf(x1, 0.0f), 1.0f);
  out[2 * NPIX + p] = (s2 > 0) ? fminf(x2 + EPSF, 1.0f)
                    : (s2 < 0) ? fmaxf(x2 - EPSF, 0.0f)
                               : fminf(fmaxf(x2, 0.0f), 1.0f);
}

extern "C" void kernel_launch(void* const* d_in, const int* in_sizes, int n_in,
                              void* d_out, int out_size, void* d_ws, size_t ws_size,
                              hipStream_t stream) {
  const float* x = (const float*)d_in[0];
  float* out = (float*)d_out;
  uint16_t* gtab = (uint16_t*)d_ws;                          // 86016 B, 16-aligned
  int8_t* gisign = (int8_t*)d_ws + 86016;                    // 672 B

  fused_build_kernel<<<1, 1024, 0, stream>>>(gtab, gisign);
  resolve_kernel<<<NPIX / 256, 256, 0, stream>>>(gtab, gisign, x, out);
}

// Round 11
// 71.194 us; speedup vs baseline: 1.1854x; 1.1854x over previous
//
#include <hip/hip_runtime.h>
#include <stdint.h>

// Square-attack schedule collapse for B=1, C=3, H=224, EPS=0.05, N_QUERIES=5000.
//
// R8 (3 kernels): 71.4 us. R10 (single-block fused build): 84.4 us REGRESSION
// -- concentrating RNG+bin+tree on one CU cost more than the saved dispatch.
// R11: keep 2 dispatches but parallelize the build across 25 blocks:
// one block per (seg, channel) table (24 independent tables; block recomputes
// only its segment's RNG, bins into private 224-entry LDS, builds its own
// 8-level range-max tree, writes 3.5 KB), block 24 does the 672 init signs.
// ~40 us of total is the harness's 0xAA d_ws poison fill (fixed floor).
//
// RNG: JAX threefry2x32, jax_threefry_partitionable=True (verified exact):
//   fold_in(key, d)          = tf(key, (0, d))
//   split(k)                 = k1 = tf(k,(0,0)), k2 = tf(k,(0,1))
//   random_bits(key,32,n)[i] = X0 ^ X1 of tf(key, (0, i))

#define HH 224
#define NQ 5000
#define NPIX (HH * HH)      // 50176 = 196 * 256
#define EPSF 0.05f
#define NTAB (8 * 3 * 8 * 224)   // [seg][c][k][v] u16 = 43008 elems = 86016 B

__device__ __forceinline__ void tf2x32(uint32_t k0, uint32_t k1,
                                       uint32_t x0, uint32_t x1,
                                       uint32_t& o0, uint32_t& o1) {
  uint32_t ks2 = k0 ^ k1 ^ 0x1BD11BDAu;
  x0 += k0; x1 += k1;
#define TFR(r) { x0 += x1; x1 = (x1 << (r)) | (x1 >> (32 - (r))); x1 ^= x0; }
  TFR(13) TFR(15) TFR(26) TFR(6)
  x0 += k1;  x1 += ks2 + 1u;
  TFR(17) TFR(29) TFR(16) TFR(24)
  x0 += ks2; x1 += k0 + 2u;
  TFR(13) TFR(15) TFR(26) TFR(6)
  x0 += k0;  x1 += k1 + 3u;
  TFR(17) TFR(29) TFR(16) TFR(24)
  x0 += k1;  x1 += ks2 + 4u;
  TFR(13) TFR(15) TFR(26) TFR(6)
  x0 += ks2; x1 += k0 + 5u;
#undef TFR
  o0 = x0; o1 = x1;
}

__device__ __forceinline__ int sign_from_bits(uint32_t bits) {
  uint32_t mant = bits >> 9;
  return (mant > 0x400000u) ? 1 : ((mant < 0x400000u) ? -1 : 0);
}

__device__ __forceinline__ float u01_from_bits(uint32_t bits) {
  return __uint_as_float(0x3f800000u | (bits >> 9)) - 1.0f;
}

__constant__ int SEG_LO_C[8] = {0, 11, 51, 201, 501, 1001, 2001, 4001};
__constant__ int SEG_HI_C[8] = {10, 50, 200, 500, 1000, 2000, 4000, 4999};
__constant__ int SEG_SZ_C[8] = {200, 142, 100, 71, 50, 35, 25, 18};

// --- Kernel 1: 25 blocks x 512. Blocks 0..23 = (seg, c): recompute segment
// RNG, bin by vh (atomicMax of ((t+1)<<1 | sign>0)), build 8-level range-max
// tree, write 3584 B. Block 24: 672 init stripe signs.
__global__ __launch_bounds__(512) void build_kernel(uint16_t* __restrict__ gtab,
                                                    int8_t* __restrict__ gisign) {
  int blk = blockIdx.x;
  int tid = threadIdx.x;

  if (blk == 24) {   // init signs: k0 = fold_in(base,0); bits[n] = X0^X1 of tf(k0,(0,n))
    uint32_t g0, g1;
    tf2x32(0u, 1u, 0u, 0u, g0, g1);
    for (int i = tid; i < 3 * HH; i += 512) {
      uint32_t o0, o1;
      tf2x32(g0, g1, 0u, (uint32_t)i, o0, o1);
      gisign[i] = (int8_t)sign_from_bits(o0 ^ o1);
    }
    return;
  }

  int seg = blk / 3, c = blk % 3;
  int s = SEG_SZ_C[seg];
  __shared__ uint32_t bins[224];
  __shared__ uint16_t tab[8 * 224];
  if (tid < 224) bins[tid] = 0;
  __syncthreads();

  for (int t = SEG_LO_C[seg] + tid; t <= SEG_HI_C[seg]; t += 512) {
    uint32_t f0, f1;
    tf2x32(0u, 1u, 0u, (uint32_t)(t + 1), f0, f1);      // k = fold_in(base, t+1)
    uint32_t a0, a1, b0, b1;
    tf2x32(f0, f1, 0u, 0u, a0, a1);                     // k1 = tf(k, (0,0))
    tf2x32(f0, f1, 0u, 1u, b0, b1);                     // k2 = tf(k, (0,1))
    uint32_t u0, u1;
    tf2x32(a0, a1, 0u, 0u, u0, u1);                     // scalar uniform bits
    int vh = (int)floorf(u01_from_bits(u0 ^ u1) * (float)(HH - s));
    uint32_t c0, c1;
    tf2x32(b0, b1, 0u, (uint32_t)c, c0, c1);            // this channel's sign bits
    int g = sign_from_bits(c0 ^ c1);
    if (g) atomicMax(&bins[vh], (((uint32_t)(t + 1)) << 1) | (uint32_t)(g > 0));
  }
  __syncthreads();

  if (tid < 224) tab[tid] = (uint16_t)bins[tid];        // tree level 0
  __syncthreads();
  for (int k = 1; k < 8; ++k) {
    int w = 1 << (k - 1);
    if (tid < 224) {
      uint16_t a = tab[(k - 1) * 224 + tid];
      uint16_t b = (tid + w < 224) ? tab[(k - 1) * 224 + tid + w] : (uint16_t)0;
      tab[k * 224 + tid] = (a > b) ? a : b;
    }
    __syncthreads();
  }

  const uint32_t* t32 = (const uint32_t*)tab;
  uint32_t* g32 = (uint32_t*)(gtab + (seg * 3 + c) * 1792);   // 1792 u16 = 896 u32
  for (int i = tid; i < 896; i += 512) g32[i] = t32[i];
}

// --- Kernel 2: stage table to LDS; per pixel, 8 O(1) range-max queries per
// channel (48 independent u16 LDS loads); emit rail value.
__global__ __launch_bounds__(256) void resolve_kernel(const uint16_t* __restrict__ gtab,
                                                      const int8_t* __restrict__ isign,
                                                      const float* __restrict__ x,
                                                      float* __restrict__ out) {
  __shared__ uint16_t tab[NTAB];           // 86016 B
  {
    float4* t4 = (float4*)tab;
    const float4* g4 = (const float4*)gtab;
    for (int i = threadIdx.x; i < NTAB * 2 / 16; i += 256) t4[i] = g4[i];
  }
  __syncthreads();

  int p = blockIdx.x * 256 + threadIdx.x;   // 0..50175
  int pi = p / HH, pj = p % HH;
  int m = min(pi, pj), M = max(pi, pj);

  const int SEG_S[8] = {200, 142, 100, 71, 50, 35, 25, 18};
  uint32_t best0 = 0, best1 = 0, best2 = 0;
#pragma unroll
  for (int seg = 0; seg < 8; ++seg) {
    const int s = SEG_S[seg];
    int lo = max(0, M - s + 1);
    int hi = min(m, 223 - s);
    bool ok = (lo <= hi);
    int len = ok ? (hi - lo + 1) : 1;
    int k = 31 - __clz(len);
    int o2 = hi + 1 - (1 << k);             // >= lo >= 0 when ok; == hi when !ok
    int b = seg * 5376 + k * 224;           // c stride = 8*224 = 1792
    uint32_t v0 = max((uint32_t)tab[b + lo],        (uint32_t)tab[b + o2]);
    uint32_t v1 = max((uint32_t)tab[b + 1792 + lo], (uint32_t)tab[b + 1792 + o2]);
    uint32_t v2 = max((uint32_t)tab[b + 3584 + lo], (uint32_t)tab[b + 3584 + o2]);
    if (!ok) { v0 = 0u; v1 = 0u; v2 = 0u; }
    best0 = max(best0, v0);
    best1 = max(best1, v1);
    best2 = max(best2, v2);
  }

  int s0 = best0 ? ((best0 & 1u) ? 1 : -1) : (int)isign[pj];
  int s1 = best1 ? ((best1 & 1u) ? 1 : -1) : (int)isign[HH + pj];
  int s2 = best2 ? ((best2 & 1u) ? 1 : -1) : (int)isign[2 * HH + pj];

  float x0 = x[p];
  float x1 = x[NPIX + p];
  float x2 = x[2 * NPIX + p];
  out[p]            = (s0 > 0) ? fminf(x0 + EPSF, 1.0f)
                    : (s0 < 0) ? fmaxf(x0 - EPSF, 0.0f)
                               : fminf(fmaxf(x0, 0.0f), 1.0f);
  out[NPIX + p]     = (s1 > 0) ? fminf(x1 + EPSF, 1.0f)
                    : (s1 < 0) ? fmaxf(x1 - EPSF, 0.0f)
                               : fminf(fmaxf(x1, 0.0f), 1.0f);
  out[2 * NPIX + p] = (s2 > 0) ? fminf(x2 + EPSF, 1.0f)
                    : (s2 < 0) ? fmaxf(x2 - EPSF, 0.0f)
                               : fminf(fmaxf(x2, 0.0f), 1.0f);
}

extern "C" void kernel_launch(void* const* d_in, const int* in_sizes, int n_in,
                              void* d_out, int out_size, void* d_ws, size_t ws_size,
                              hipStream_t stream) {
  const float* x = (const float*)d_in[0];
  float* out = (float*)d_out;
  uint16_t* gtab = (uint16_t*)d_ws;                          // 86016 B, 16-aligned
  int8_t* gisign = (int8_t*)d_ws + 86016;                    // 672 B

  build_kernel<<<25, 512, 0, stream>>>(gtab, gisign);
  resolve_kernel<<<NPIX / 256, 256, 0, stream>>>(gtab, gisign, x, out);
}

// Round 13
// 66.086 us; speedup vs baseline: 1.2770x; 1.0773x over previous
//
#include <hip/hip_runtime.h>
#include <stdint.h>

// Square-attack schedule collapse for B=1, C=3, H=224, EPS=0.05, N_QUERIES=5000.
//
// R11 decomposition (with R5's slack<=2us calibration): 71.2 = 40 (harness
// 0xAA d_ws poison fill, fixed floor) + ~2 build + ~27 RESOLVE. Resolve was
// latency-bound: 86KB LDS/block -> 1 wave/SIMD, zero TLP, 21 staging
// round-trips + 48 LDS-read chains fully exposed.
// R12: no-LDS resolve. Table (86KB) stays in L2 (per-XCD resident after first
// touch); one thread per (pixel,channel) via grid(196,3); 16 independent u16
// global loads per thread, lanes hit 1-2 consecutive cachelines per query.
// Occupancy-hidden latency instead of staging.
//
// RNG: JAX threefry2x32, jax_threefry_partitionable=True (verified exact):
//   fold_in(key, d)          = tf(key, (0, d))
//   split(k)                 = k1 = tf(k,(0,0)), k2 = tf(k,(0,1))
//   random_bits(key,32,n)[i] = X0 ^ X1 of tf(key, (0, i))

#define HH 224
#define NQ 5000
#define NPIX (HH * HH)      // 50176 = 196 * 256
#define EPSF 0.05f

__device__ __forceinline__ void tf2x32(uint32_t k0, uint32_t k1,
                                       uint32_t x0, uint32_t x1,
                                       uint32_t& o0, uint32_t& o1) {
  uint32_t ks2 = k0 ^ k1 ^ 0x1BD11BDAu;
  x0 += k0; x1 += k1;
#define TFR(r) { x0 += x1; x1 = (x1 << (r)) | (x1 >> (32 - (r))); x1 ^= x0; }
  TFR(13) TFR(15) TFR(26) TFR(6)
  x0 += k1;  x1 += ks2 + 1u;
  TFR(17) TFR(29) TFR(16) TFR(24)
  x0 += ks2; x1 += k0 + 2u;
  TFR(13) TFR(15) TFR(26) TFR(6)
  x0 += k0;  x1 += k1 + 3u;
  TFR(17) TFR(29) TFR(16) TFR(24)
  x0 += k1;  x1 += ks2 + 4u;
  TFR(13) TFR(15) TFR(26) TFR(6)
  x0 += ks2; x1 += k0 + 5u;
#undef TFR
  o0 = x0; o1 = x1;
}

__device__ __forceinline__ int sign_from_bits(uint32_t bits) {
  uint32_t mant = bits >> 9;
  return (mant > 0x400000u) ? 1 : ((mant < 0x400000u) ? -1 : 0);
}

__device__ __forceinline__ float u01_from_bits(uint32_t bits) {
  return __uint_as_float(0x3f800000u | (bits >> 9)) - 1.0f;
}

__constant__ int SEG_LO_C[8] = {0, 11, 51, 201, 501, 1001, 2001, 4001};
__constant__ int SEG_HI_C[8] = {10, 50, 200, 500, 1000, 2000, 4000, 4999};
__constant__ int SEG_SZ_C[8] = {200, 142, 100, 71, 50, 35, 25, 18};

// --- Kernel 1: 25 blocks x 512. Blocks 0..23 = (seg, c): recompute segment
// RNG, bin by vh (atomicMax of ((t+1)<<1 | sign>0)), build 8-level range-max
// tree, write 3584 B. Block 24: 672 init stripe signs. (R11-verified.)
__global__ __launch_bounds__(512) void build_kernel(uint16_t* __restrict__ gtab,
                                                    int8_t* __restrict__ gisign) {
  int blk = blockIdx.x;
  int tid = threadIdx.x;

  if (blk == 24) {   // init signs: k0 = fold_in(base,0); bits[n] = X0^X1 of tf(k0,(0,n))
    uint32_t g0, g1;
    tf2x32(0u, 1u, 0u, 0u, g0, g1);
    for (int i = tid; i < 3 * HH; i += 512) {
      uint32_t o0, o1;
      tf2x32(g0, g1, 0u, (uint32_t)i, o0, o1);
      gisign[i] = (int8_t)sign_from_bits(o0 ^ o1);
    }
    return;
  }

  int seg = blk / 3, c = blk % 3;
  int s = SEG_SZ_C[seg];
  __shared__ uint32_t bins[224];
  __shared__ uint16_t tab[8 * 224];
  if (tid < 224) bins[tid] = 0;
  __syncthreads();

  for (int t = SEG_LO_C[seg] + tid; t <= SEG_HI_C[seg]; t += 512) {
    uint32_t f0, f1;
    tf2x32(0u, 1u, 0u, (uint32_t)(t + 1), f0, f1);      // k = fold_in(base, t+1)
    uint32_t a0, a1, b0, b1;
    tf2x32(f0, f1, 0u, 0u, a0, a1);                     // k1 = tf(k, (0,0))
    tf2x32(f0, f1, 0u, 1u, b0, b1);                     // k2 = tf(k, (0,1))
    uint32_t u0, u1;
    tf2x32(a0, a1, 0u, 0u, u0, u1);                     // scalar uniform bits
    int vh = (int)floorf(u01_from_bits(u0 ^ u1) * (float)(HH - s));
    uint32_t c0, c1;
    tf2x32(b0, b1, 0u, (uint32_t)c, c0, c1);            // this channel's sign bits
    int g = sign_from_bits(c0 ^ c1);
    if (g) atomicMax(&bins[vh], (((uint32_t)(t + 1)) << 1) | (uint32_t)(g > 0));
  }
  __syncthreads();

  if (tid < 224) tab[tid] = (uint16_t)bins[tid];        // tree level 0
  __syncthreads();
  for (int k = 1; k < 8; ++k) {
    int w = 1 << (k - 1);
    if (tid < 224) {
      uint16_t a = tab[(k - 1) * 224 + tid];
      uint16_t b = (tid + w < 224) ? tab[(k - 1) * 224 + tid + w] : (uint16_t)0;
      tab[k * 224 + tid] = (a > b) ? a : b;
    }
    __syncthreads();
  }

  const uint32_t* t32 = (const uint32_t*)tab;
  uint32_t* g32 = (uint32_t*)(gtab + (seg * 3 + c) * 1792);   // 1792 u16 = 896 u32
  for (int i = tid; i < 896; i += 512) g32[i] = t32[i];
}

// --- Kernel 2: one thread per (pixel, channel); 16 independent u16 global
// loads (8 segs x 2, L2-resident table); emit rail value. No LDS.
__global__ __launch_bounds__(256) void resolve_kernel(const uint16_t* __restrict__ gtab,
                                                      const int8_t* __restrict__ isign,
                                                      const float* __restrict__ x,
                                                      float* __restrict__ out) {
  int c = blockIdx.y;
  int p = blockIdx.x * 256 + threadIdx.x;   // 0..50175
  int pi = p / HH, pj = p % HH;
  int m = min(pi, pj), M = max(pi, pj);

  const uint16_t* tc = gtab + c * 1792;     // [seg][c][k][v]: + seg*5376 + k*224 + v

  const int SEG_S[8] = {200, 142, 100, 71, 50, 35, 25, 18};
  uint32_t best = 0;
#pragma unroll
  for (int seg = 0; seg < 8; ++seg) {
    const int s = SEG_S[seg];
    int lo = max(0, M - s + 1);
    int hi = min(m, 223 - s);
    bool ok = (lo <= hi);
    int len = ok ? (hi - lo + 1) : 1;
    int k = 31 - __clz(len);
    int o2 = hi + 1 - (1 << k);             // >= lo >= 0 when ok; == hi when !ok
    int b = seg * 5376 + k * 224;
    uint32_t v = max((uint32_t)tc[b + lo], (uint32_t)tc[b + o2]);
    best = max(best, ok ? v : 0u);
  }

  int sg = best ? ((best & 1u) ? 1 : -1) : (int)isign[c * HH + pj];

  int idx = c * NPIX + p;
  float xv = x[idx];
  out[idx] = (sg > 0) ? fminf(xv + EPSF, 1.0f)
           : (sg < 0) ? fmaxf(xv - EPSF, 0.0f)
                      : fminf(fmaxf(xv, 0.0f), 1.0f);
}

extern "C" void kernel_launch(void* const* d_in, const int* in_sizes, int n_in,
                              void* d_out, int out_size, void* d_ws, size_t ws_size,
                              hipStream_t stream) {
  const float* x = (const float*)d_in[0];
  float* out = (float*)d_out;
  uint16_t* gtab = (uint16_t*)d_ws;                          // 86016 B, 16-aligned
  int8_t* gisign = (int8_t*)d_ws + 86016;                    // 672 B

  build_kernel<<<25, 512, 0, stream>>>(gtab, gisign);
  dim3 rgrid(NPIX / 256, 3);
  resolve_kernel<<<rgrid, 256, 0, stream>>>(gtab, gisign, x, out);
}